// Round 5
// baseline (290.481 us; speedup 1.0000x reference)
//
#include <hip/hip_runtime.h>

// L_p[b,d] = sum_e (sum_f Theta[d,f] * X[b,f,e])^2
// B=16384, F=50, E=64, D=128, fp32 in/out; bf16 MFMA compute.
//
// Pipeline per iter: load_regs(b+2) [global->VGPR, stays IN FLIGHT across
// barriers] ; compute(b) from LDS ; cvt_write(b+1) -> LDS other buffer ;
// barrier_lds(). barrier_lds = s_waitcnt lgkmcnt(0) + s_barrier ONLY --
// no vmcnt(0) drain (prefetches are wave-private registers; __syncthreads'
// workgroup fence would drain them and expose full HBM latency every iter).
// MFMA orientation (mfma_f32_16x16x32_bf16):
//   A[m=e(lane&15)][k=f(quad*8+j)]  <- ds_read_b128 from LDS (shared by 4 waves)
//   B[k=f][n=d(lane&15)]            <- Theta, preloaded in regs (wave owns 32 d's)
//   C/D: col(lane&15)=d, row(quad*4+reg)=e -> squared-sum = 32 fma + 2 shfl_xor.

#define NB 8
constexpr int kF  = 50;
constexpr int kE  = 64;
constexpr int kD  = 128;
constexpr int kFE = kF * kE;  // 3200
constexpr int FS  = 72;       // LDS row stride in shorts (16B-aligned b128 reads)

typedef __attribute__((ext_vector_type(8))) short short8;
typedef __attribute__((ext_vector_type(4))) short bf16x4;
typedef __attribute__((ext_vector_type(4))) float f32x4;

__device__ __forceinline__ short f2bf(float f) {
  // round-to-nearest-even fp32 -> bf16
  unsigned u = __float_as_uint(f);
  u += 0x7FFFu + ((u >> 16) & 1u);
  return (short)(u >> 16);
}

// Workgroup barrier ordering LDS only. Keeps global prefetch loads in flight.
__device__ __forceinline__ void barrier_lds() {
  asm volatile("s_waitcnt lgkmcnt(0)\n\ts_barrier" ::: "memory");
}

__global__ __launch_bounds__(256, 4) void ip_kernel(
    const float* __restrict__ X, const float* __restrict__ Th,
    float* __restrict__ out) {
  __shared__ __align__(16) short lds[2][kE * FS];  // 2 x 9216 shorts = 18432 B

  const int tid  = threadIdx.x;
  const int wid  = tid >> 6;   // wave id: owns d in [32*wid,+32); staging f-group
  const int lane = tid & 63;
  const int q    = lane >> 4;  // quad
  const int m16  = lane & 15;
  const int se   = lane;       // staging e coordinate (0..63)

  // ---- zero tail f in [52,64) once (read by ks=1 A-frags, never re-written) ----
  for (int i = tid; i < kE * 12 * 2; i += 256) {
    const int buf = (i >= kE * 12) ? 1 : 0;
    const int r = i - buf * kE * 12;
    lds[buf][(r / 12) * FS + 52 + (r % 12)] = 0;
  }

  // ---- Theta B-frags: th[dt][ks][j] = Theta[d0+16dt+m16][32ks+8q+j], 0 if f>=50 ----
  short8 th[2][2];
  const int d0 = wid * 32;
#pragma unroll
  for (int dt = 0; dt < 2; ++dt) {
    const float* trow = Th + (size_t)(d0 + dt * 16 + m16) * kF;
#pragma unroll
    for (int ks = 0; ks < 2; ++ks) {
      short8 v;
#pragma unroll
      for (int j = 0; j < 8; ++j) {
        const int k = ks * 32 + q * 8 + j;
        v[j] = (k < kF) ? f2bf(trow[k]) : (short)0;
      }
      th[dt][ks] = v;
    }
  }

  const int b0 = blockIdx.x * NB;

  // Two in-flight register sets. Thread (se, wid) owns f = 16p+4*wid+j (p<3,j<4);
  // wave 0 additionally owns f = 48,49.
  float xr[2][14];

  auto load_regs = [&](int set, int b) {
    const float* xb = X + (size_t)b * kFE + se;
#pragma unroll
    for (int p = 0; p < 3; ++p)
#pragma unroll
      for (int j = 0; j < 4; ++j)
        xr[set][p * 4 + j] = xb[(16 * p + 4 * wid + j) * kE];
    if (wid == 0) {  // wave-uniform branch
      xr[set][12] = xb[48 * kE];
      xr[set][13] = xb[49 * kE];
    }
  };

  auto cvt_write = [&](int set, int buf) {
    short* row = &lds[buf][se * FS];
#pragma unroll
    for (int p = 0; p < 3; ++p) {
      bf16x4 w;
#pragma unroll
      for (int j = 0; j < 4; ++j) w[j] = f2bf(xr[set][p * 4 + j]);
      *reinterpret_cast<bf16x4*>(&row[16 * p + 4 * wid]) = w;
    }
    if (wid == 0) {  // f = 48,49 (+ zero 50,51)
      bf16x4 w;
      w[0] = f2bf(xr[set][12]);
      w[1] = f2bf(xr[set][13]);
      w[2] = 0; w[3] = 0;
      *reinterpret_cast<bf16x4*>(&row[48]) = w;
    }
  };

  auto compute_store = [&](int cur, int b) {
    const short* L = &lds[cur][m16 * FS + q * 8];
    f32x4 acc[4][2];
#pragma unroll
    for (int et = 0; et < 4; ++et)
#pragma unroll
      for (int dt = 0; dt < 2; ++dt) acc[et][dt] = (f32x4){0.f, 0.f, 0.f, 0.f};

#pragma unroll
    for (int et = 0; et < 4; ++et) {
      const short8 a0 = *reinterpret_cast<const short8*>(&L[et * 16 * FS]);
      const short8 a1 = *reinterpret_cast<const short8*>(&L[et * 16 * FS + 32]);
#pragma unroll
      for (int dt = 0; dt < 2; ++dt) {
        acc[et][dt] = __builtin_amdgcn_mfma_f32_16x16x32_bf16(a0, th[dt][0], acc[et][dt], 0, 0, 0);
        acc[et][dt] = __builtin_amdgcn_mfma_f32_16x16x32_bf16(a1, th[dt][1], acc[et][dt], 0, 0, 0);
      }
    }

    float sv[2];
#pragma unroll
    for (int dt = 0; dt < 2; ++dt) {
      float s = 0.0f;
#pragma unroll
      for (int et = 0; et < 4; ++et)
#pragma unroll
        for (int r = 0; r < 4; ++r) {
          const float p = acc[et][dt][r];
          s = fmaf(p, p, s);
        }
      s += __shfl_xor(s, 16, 64);
      s += __shfl_xor(s, 32, 64);
      sv[dt] = s;
    }
    if (lane < 32) out[(size_t)b * kD + d0 + lane] = (lane < 16) ? sv[0] : sv[1];
  };

  // ---- prologue: fill buf0 with b0, issue loads for b0+1 ----
  load_regs(0, b0);
  cvt_write(0, 0);
  load_regs(1, b0 + 1);
  barrier_lds();

  // ---- main loop, hand-unrolled x2 so set/buffer indices are constants ----
  for (int ibb = 0; ibb < NB; ibb += 2) {
    {
      const int ib = ibb;
      if (ib + 2 < NB) load_regs(0, b0 + ib + 2);
      compute_store(0, b0 + ib);
      cvt_write(1, 1);  // ib+1 <= NB-1 always for even ib
      barrier_lds();
    }
    {
      const int ib = ibb + 1;
      if (ib + 2 < NB) load_regs(1, b0 + ib + 2);
      compute_store(1, b0 + ib);
      if (ib + 1 < NB) cvt_write(0, 0);
      barrier_lds();
    }
  }
}

extern "C" void kernel_launch(void* const* d_in, const int* in_sizes, int n_in,
                              void* d_out, int out_size, void* d_ws, size_t ws_size,
                              hipStream_t stream) {
  const float* X  = (const float*)d_in[0];  // [16384, 50, 64] fp32
  const float* Th = (const float*)d_in[1];  // [128, 50] fp32
  float* out = (float*)d_out;               // [16384, 128] fp32
  ip_kernel<<<dim3(16384 / NB), dim3(256), 0, stream>>>(X, Th, out);
}